// Round 5
// baseline (4688.799 us; speedup 1.0000x reference)
//
#include <hip/hip_runtime.h>

// 6-layer LSTM, B=64, S=2048, I=64, H=128, G=512.
// Design: wg = (layer, batch-block of 16). 24 active wgs, layers pipelined
// via ring buffers + device-scope atomic flags in d_ws (chunked, 16 steps).
// Weights register-resident as bf16 MFMA B-fragments. Recurrent h is
// wg-local in LDS (XOR-swizzled, ping-pong). MFMA 16x16x32 bf16, f32 acc.

#define NLAYERS 6
#define BATCH   64
#define SEQ     2048
#define ISZ     64
#define HID     128
#define GD      512
#define CHUNK   16
#define NSLOT   2
#define MB      16
#define NCHAIN  4
#define NCHUNKS (SEQ / CHUNK)

#define SLOT_BYTES (CHUNK * MB * HID * 2)   // 65536 B per published chunk
#define IF_BYTES   (NSLOT * SLOT_BYTES)     // 131072 B per interface
#define PROG_OFF   0
#define CONS_OFF   4096
#define RING_OFF   8192
#define LDS_IN_OFF  0
#define LDS_OUT_OFF 65536
#define LDS_H_OFF   131072
#define LDS_TOTAL   139264                  // 136 KiB <= 160 KiB

typedef __attribute__((ext_vector_type(8))) short bf16x8;
typedef __attribute__((ext_vector_type(4))) float f32x4;

__device__ __forceinline__ short f2bf(float f) {
  union { float f; unsigned u; } v; v.f = f;
  unsigned r = v.u + 0x7fffu + ((v.u >> 16) & 1u);   // RNE
  return (short)(r >> 16);
}
__device__ __forceinline__ float sigm(float x)  { return 1.0f / (1.0f + __expf(-x)); }
__device__ __forceinline__ float tanh_f(float x){ return 1.0f - 2.0f / (__expf(2.0f * x) + 1.0f); }

template <int KT_IN>
__device__ __forceinline__ void lstm_chain(
    int layer, int beta,
    const float* __restrict__ x,    const float* __restrict__ h0,
    const float* __restrict__ c0,   const float* __restrict__ wih0,
    const float* __restrict__ wihr, const float* __restrict__ whh,
    const float* __restrict__ bih,  const float* __restrict__ bhh,
    float* __restrict__ out, char* __restrict__ ws, char* smem)
{
  constexpr int KT   = KT_IN + 4;       // total K-tiles (32 each)
  constexpr int K_IN = KT_IN * 32;      // 64 (layer 0, from x) or 128
  constexpr int RS   = K_IN * 2;        // lds_in row bytes
  constexpr int INB  = MB * RS;         // lds_in bytes per step-slot

  char* lds_in  = smem + LDS_IN_OFF;    // staged chunk input (16 steps)
  char* lds_out = smem + LDS_OUT_OFF;   // chunk output accumulation
  char* lds_h   = smem + LDS_H_OFF;     // 2 x 4KB ping-pong recurrent h

  const int tid  = threadIdx.x;
  const int w    = tid >> 6;            // wave 0..7, owns units [w*16, w*16+16)
  const int lane = tid & 63;
  const int lrow = lane & 15;           // MFMA row/col lane index
  const int lkg  = lane >> 4;           // MFMA k-group / acc row group

  // ---- weights -> register-resident bf16 B-fragments (one-time) ----
  // B[k][n] = W[gate_row = n][k]; lane: n = lrow, k = kt*32 + lkg*8 + e
  const float* Wih = (KT_IN == 2) ? wih0 : (wihr + (size_t)(layer - 1) * GD * HID);
  const float* Whh = whh + (size_t)layer * GD * HID;

  bf16x8 bfrag[4][KT];
  #pragma unroll
  for (int gt = 0; gt < 4; ++gt) {
    const int gr = gt * 128 + w * 16 + lrow;
    #pragma unroll
    for (int kt = 0; kt < KT; ++kt) {
      short tmp[8];
      #pragma unroll
      for (int eh = 0; eh < 2; ++eh) {
        const int k = kt * 32 + lkg * 8 + eh * 4;
        const float* src = (k < K_IN) ? (Wih + (size_t)gr * K_IN + k)
                                      : (Whh + (size_t)gr * HID + (k - K_IN));
        float4 v = *(const float4*)src;
        tmp[eh*4+0] = f2bf(v.x); tmp[eh*4+1] = f2bf(v.y);
        tmp[eh*4+2] = f2bf(v.z); tmp[eh*4+3] = f2bf(v.w);
      }
      bfrag[gt][kt] = (bf16x8){tmp[0],tmp[1],tmp[2],tmp[3],tmp[4],tmp[5],tmp[6],tmp[7]};
    }
  }

  float bias[4];
  #pragma unroll
  for (int gt = 0; gt < 4; ++gt) {
    const int gr = gt * 128 + w * 16 + lrow;
    bias[gt] = bih[layer * GD + gr] + bhh[layer * GD + gr];
  }

  // ---- init c (f32 regs) and h_{-1} -> lds_h parity 1 ----
  float creg[4], hlast[4];
  {
    const int j = w * 16 + lrow;
    #pragma unroll
    for (int r = 0; r < 4; ++r) {
      const int m = lkg * 4 + r;
      const int b = beta * MB + m;
      creg[r]  = c0[((size_t)layer * BATCH + b) * HID + j];
      float hv = h0[((size_t)layer * BATCH + b) * HID + j];
      hlast[r] = hv;
      const int byte = (m * 256 + j * 2) ^ ((m & 7) << 4);
      *(short*)(lds_h + 4096 + byte) = f2bf(hv);
    }
  }

  // ---- flags / rings (interface i = beta*5 + producer_layer) ----
  int*  prog_up = (int*)(ws + PROG_OFF + (size_t)(beta * 5 + layer - 1) * 128);
  int*  prog_dn = (int*)(ws + PROG_OFF + (size_t)(beta * 5 + layer) * 128);
  int*  cons_up = (int*)(ws + CONS_OFF + (size_t)(beta * 5 + layer - 1) * 128);
  int*  cons_dn = (int*)(ws + CONS_OFF + (size_t)(beta * 5 + layer) * 128);
  char* ring_up = ws + RING_OFF + (size_t)(beta * 5 + layer - 1) * IF_BYTES;
  char* ring_dn = ws + RING_OFF + (size_t)(beta * 5 + layer) * IF_BYTES;

  for (int q = 0; q < NCHUNKS; ++q) {
    // ================= stage chunk input into lds_in =================
    if (KT_IN == 2) {
      // layer 0: x[b][t][i] f32 -> bf16, swizzled
      const int p = tid >> 1, hh = tid & 1;
      const int s = p >> 4,  m  = p & 15;
      const float* xs = x + ((size_t)(beta * MB + m) * SEQ + (q * CHUNK + s)) * ISZ + hh * 32;
      #pragma unroll
      for (int c4 = 0; c4 < 4; ++c4) {
        float4 a = *(const float4*)(xs + c4 * 8);
        float4 b = *(const float4*)(xs + c4 * 8 + 4);
        bf16x8 pv = {f2bf(a.x), f2bf(a.y), f2bf(a.z), f2bf(a.w),
                     f2bf(b.x), f2bf(b.y), f2bf(b.z), f2bf(b.w)};
        const int byte = s * INB + ((m * RS + hh * 64 + c4 * 16) ^ ((m & 7) << 4));
        *(bf16x8*)(lds_in + byte) = pv;
      }
      __syncthreads();
    } else {
      if (tid == 0) {
        while (__hip_atomic_load(prog_up, __ATOMIC_RELAXED, __HIP_MEMORY_SCOPE_AGENT) < q + 1)
          __builtin_amdgcn_s_sleep(2);
        (void)__hip_atomic_load(prog_up, __ATOMIC_ACQUIRE, __HIP_MEMORY_SCOPE_AGENT);
      }
      __syncthreads();   // acquire (L1/L2 inv) ordered before everyone's loads
      const char* slot = ring_up + (size_t)(q & (NSLOT - 1)) * SLOT_BYTES;
      #pragma unroll
      for (int c = 0; c < 8; ++c) {
        const int L = tid * 128 + c * 16;          // linear ring offset
        int4 v = *(const int4*)(slot + L);
        const int row = (L >> 8) & 15;
        *(int4*)(lds_in + (L ^ ((row & 7) << 4))) = v;  // swizzled LDS
      }
      __syncthreads();
      if (tid == 0)   // ring slot credit back to producer
        __hip_atomic_store(cons_up, q + 1, __ATOMIC_RELEASE, __HIP_MEMORY_SCOPE_AGENT);
    }

    // ================= 16 timesteps =================
    #pragma unroll 1
    for (int s = 0; s < CHUNK; ++s) {
      f32x4 acc[4];
      #pragma unroll
      for (int gt = 0; gt < 4; ++gt) acc[gt] = (f32x4){0.f, 0.f, 0.f, 0.f};

      // input half (from staged chunk; no dependence on h_{t-1})
      #pragma unroll
      for (int kt = 0; kt < KT_IN; ++kt) {
        const int byte = s * INB + ((lrow * RS + kt * 64 + lkg * 16) ^ ((lrow & 7) << 4));
        bf16x8 a = *(const bf16x8*)(lds_in + byte);
        #pragma unroll
        for (int gt = 0; gt < 4; ++gt)
          acc[gt] = __builtin_amdgcn_mfma_f32_16x16x32_bf16(a, bfrag[gt][kt], acc[gt], 0, 0, 0);
      }

      __syncthreads();   // all waves' h_{t-1} writes visible

      // recurrent half from lds_h[(s&1)^1]
      {
        char* hsrc = lds_h + ((((s & 1) ^ 1)) << 12);
        #pragma unroll
        for (int kt = 0; kt < 4; ++kt) {
          const int byte = (lrow * 256 + kt * 64 + lkg * 16) ^ ((lrow & 7) << 4);
          bf16x8 a = *(const bf16x8*)(hsrc + byte);
          #pragma unroll
          for (int gt = 0; gt < 4; ++gt)
            acc[gt] = __builtin_amdgcn_mfma_f32_16x16x32_bf16(a, bfrag[gt][KT_IN + kt], acc[gt], 0, 0, 0);
        }
      }

      // activations + state update (lane-local: i,f,g,o co-located)
      {
        char* hdst = lds_h + ((s & 1) << 12);
        const int j = w * 16 + lrow;
        #pragma unroll
        for (int r = 0; r < 4; ++r) {
          const float gi = sigm(acc[0][r] + bias[0]);
          const float gf = sigm(acc[1][r] + bias[1]);
          const float gg = tanh_f(acc[2][r] + bias[2]);
          const float go = sigm(acc[3][r] + bias[3]);
          const float c  = gf * creg[r] + gi * gg;
          creg[r] = c;
          const float h = go * tanh_f(c);
          hlast[r] = h;
          const short hb = f2bf(h);
          const int m = lkg * 4 + r;
          const int byte = (m * 256 + j * 2) ^ ((m & 7) << 4);
          *(short*)(hdst + byte) = hb;
          if (layer < 5) *(short*)(lds_out + s * 4096 + byte) = hb;
        }
      }
    }

    // ================= publish chunk to next layer =================
    if (layer < 5) {
      __syncthreads();   // lds_out complete (drains all counters)
      if (tid == 0 && q >= NSLOT) {
        while (__hip_atomic_load(cons_dn, __ATOMIC_RELAXED, __HIP_MEMORY_SCOPE_AGENT) < q + 1 - NSLOT)
          __builtin_amdgcn_s_sleep(2);
        (void)__hip_atomic_load(cons_dn, __ATOMIC_ACQUIRE, __HIP_MEMORY_SCOPE_AGENT);
      }
      __syncthreads();
      char* slot = ring_dn + (size_t)(q & (NSLOT - 1)) * SLOT_BYTES;
      #pragma unroll
      for (int c = 0; c < 8; ++c) {
        const int L = tid * 128 + c * 16;
        const int row = (L >> 8) & 15;
        int4 v = *(const int4*)(lds_out + (L ^ ((row & 7) << 4)));  // unswizzle
        *(int4*)(slot + L) = v;                                     // linear ring
      }
      __syncthreads();   // drains vmcnt: all threads' stores in L2
      if (tid == 0)      // release: wbl2 flush, then flag
        __hip_atomic_store(prog_dn, q + 1, __ATOMIC_RELEASE, __HIP_MEMORY_SCOPE_AGENT);
    }
  }

  // ---- output h_n (f32, from final-step registers) ----
  {
    const int j = w * 16 + lrow;
    #pragma unroll
    for (int r = 0; r < 4; ++r) {
      const int m = lkg * 4 + r;
      const int b = beta * MB + m;
      out[((size_t)layer * BATCH + b) * HID + j] = hlast[r];
    }
  }
}

extern "C" __global__ void __launch_bounds__(512, 2)
lstm_pipe(const float* __restrict__ x,    const float* __restrict__ h0,
          const float* __restrict__ c0,   const float* __restrict__ wih0,
          const float* __restrict__ wihr, const float* __restrict__ whh,
          const float* __restrict__ bih,  const float* __restrict__ bhh,
          float* __restrict__ out, char* __restrict__ ws)
{
  extern __shared__ char smem[];
  const int bid   = blockIdx.x;
  const int beta  = bid & 7;    // chain; bid%8 keeps a chain on one XCD
  const int layer = bid >> 3;
  if (beta >= NCHAIN) return;   // dummy blocks (XCD-alignment padding)
  if (layer == 0)
    lstm_chain<2>(layer, beta, x, h0, c0, wih0, wihr, whh, bih, bhh, out, ws, smem);
  else
    lstm_chain<4>(layer, beta, x, h0, c0, wih0, wihr, whh, bih, bhh, out, ws, smem);
}

extern "C" void kernel_launch(void* const* d_in, const int* in_sizes, int n_in,
                              void* d_out, int out_size, void* d_ws, size_t ws_size,
                              hipStream_t stream)
{
  (void)in_sizes; (void)n_in; (void)out_size; (void)ws_size;
  hipFuncSetAttribute((const void*)lstm_pipe,
                      hipFuncAttributeMaxDynamicSharedMemorySize, LDS_TOTAL);
  // zero progress/consumed flags (d_ws is poisoned 0xAA before every launch)
  hipMemsetAsync(d_ws, 0, RING_OFF, stream);
  lstm_pipe<<<dim3(48), dim3(512), LDS_TOTAL, stream>>>(
      (const float*)d_in[0], (const float*)d_in[1], (const float*)d_in[2],
      (const float*)d_in[3], (const float*)d_in[4], (const float*)d_in[5],
      (const float*)d_in[6], (const float*)d_in[7],
      (float*)d_out, (char*)d_ws);
}

// Round 6
// 4432.690 us; speedup vs baseline: 1.0578x; 1.0578x over previous
//
#include <hip/hip_runtime.h>

// 6-layer LSTM, B=64, S=2048, I=64, H=128, G=512.
// wg = (layer, batch-block of 16). 24 active wgs, layers pipelined via ring
// buffers + agent-scope atomic flags in d_ws (chunked, 16 steps). Weights
// register-resident as bf16 MFMA B-fragments. Recurrent h in LDS (XOR-
// swizzled, ping-pong). R5: software-pipelined step loop — inp-MFMA(s+1)
// prefetched into alternate acc set, interleaved with act(s); bias folded
// into acc init. (R4 counters: VALUBusy 62%/MfmaUtil 18% on active CUs,
// barrier-lockstep serialization was the bottleneck.)

#define NLAYERS 6
#define BATCH   64
#define SEQ     2048
#define ISZ     64
#define HID     128
#define GD      512
#define CHUNK   16
#define NSLOT   2
#define MB      16
#define NCHAIN  4
#define NCHUNKS (SEQ / CHUNK)

#define SLOT_BYTES (CHUNK * MB * HID * 2)   // 65536 B per published chunk
#define IF_BYTES   (NSLOT * SLOT_BYTES)     // 131072 B per interface
#define PROG_OFF   0
#define CONS_OFF   4096
#define RING_OFF   8192
#define LDS_IN_OFF  0
#define LDS_OUT_OFF 65536
#define LDS_H_OFF   131072
#define LDS_TOTAL   139264                  // 136 KiB <= 160 KiB

typedef __attribute__((ext_vector_type(8))) short bf16x8;
typedef __attribute__((ext_vector_type(4))) float f32x4;

__device__ __forceinline__ short f2bf(float f) {
  union { float f; unsigned u; } v; v.f = f;
  unsigned r = v.u + 0x7fffu + ((v.u >> 16) & 1u);   // RNE
  return (short)(r >> 16);
}
__device__ __forceinline__ float sigm(float x)  { return 1.0f / (1.0f + __expf(-x)); }
__device__ __forceinline__ float tanh_f(float x){ return 1.0f - 2.0f / (__expf(2.0f * x) + 1.0f); }

// ---- step-loop macros (static acc names; rule #20: no runtime-indexed regs) ----
// Init NXT with bias and accumulate the input-half MFMAs for step SN.
#define INP_PREF(NXT, SN)                                                      \
  do {                                                                         \
    _Pragma("unroll")                                                          \
    for (int gt = 0; gt < 4; ++gt)                                             \
      NXT[gt] = (f32x4){bias[gt], bias[gt], bias[gt], bias[gt]};               \
    _Pragma("unroll")                                                          \
    for (int kt = 0; kt < KT_IN; ++kt) {                                       \
      const int bytei = (SN) * INB + ((lrow * RS + kt * 64 + lkg * 16) ^ ((lrow & 7) << 4)); \
      bf16x8 a = *(const bf16x8*)(lds_in + bytei);                             \
      _Pragma("unroll")                                                        \
      for (int gt = 0; gt < 4; ++gt)                                           \
        NXT[gt] = __builtin_amdgcn_mfma_f32_16x16x32_bf16(a, bfrag[gt][kt], NXT[gt], 0, 0, 0); \
    }                                                                          \
  } while (0)

// One timestep: barrier; recurrent-half MFMA into CUR; (opt) prefetch input
// half of step S+1 into NXT; activations + h/lds_out writes from CUR.
#define DO_STEP(CUR, NXT, S, PREF)                                             \
  do {                                                                         \
    __syncthreads();                                                           \
    {                                                                          \
      char* hsrc = lds_h + ((((S) & 1) ^ 1) << 12);                            \
      _Pragma("unroll")                                                        \
      for (int kt = 0; kt < 4; ++kt) {                                         \
        const int byteh = (lrow * 256 + kt * 64 + lkg * 16) ^ ((lrow & 7) << 4); \
        bf16x8 a = *(const bf16x8*)(hsrc + byteh);                             \
        _Pragma("unroll")                                                      \
        for (int gt = 0; gt < 4; ++gt)                                         \
          CUR[gt] = __builtin_amdgcn_mfma_f32_16x16x32_bf16(a, bfrag[gt][KT_IN + kt], CUR[gt], 0, 0, 0); \
      }                                                                        \
    }                                                                          \
    if (PREF) { INP_PREF(NXT, (S) + 1); }                                      \
    {                                                                          \
      char* hdst = lds_h + (((S) & 1) << 12);                                  \
      _Pragma("unroll")                                                        \
      for (int r = 0; r < 4; ++r) {                                            \
        const float gi = sigm(CUR[0][r]);                                      \
        const float gf = sigm(CUR[1][r]);                                      \
        const float gg = tanh_f(CUR[2][r]);                                    \
        const float go = sigm(CUR[3][r]);                                      \
        const float c  = gf * creg[r] + gi * gg;                               \
        creg[r] = c;                                                           \
        const float h = go * tanh_f(c);                                        \
        hlast[r] = h;                                                          \
        const short hb = f2bf(h);                                              \
        const int m = lkg * 4 + r;                                             \
        const int byteo = (m * 256 + jj * 2) ^ ((m & 7) << 4);                 \
        *(short*)(hdst + byteo) = hb;                                          \
        if (layer < 5) *(short*)(lds_out + (S) * 4096 + byteo) = hb;           \
      }                                                                        \
    }                                                                          \
  } while (0)

template <int KT_IN>
__device__ __forceinline__ void lstm_chain(
    int layer, int beta,
    const float* __restrict__ x,    const float* __restrict__ h0,
    const float* __restrict__ c0,   const float* __restrict__ wih0,
    const float* __restrict__ wihr, const float* __restrict__ whh,
    const float* __restrict__ bih,  const float* __restrict__ bhh,
    float* __restrict__ out, char* __restrict__ ws, char* smem)
{
  constexpr int KT   = KT_IN + 4;       // total K-tiles (32 each)
  constexpr int K_IN = KT_IN * 32;      // 64 (layer 0, from x) or 128
  constexpr int RS   = K_IN * 2;        // lds_in row bytes
  constexpr int INB  = MB * RS;         // lds_in bytes per step-slot

  char* lds_in  = smem + LDS_IN_OFF;    // staged chunk input (16 steps)
  char* lds_out = smem + LDS_OUT_OFF;   // chunk output accumulation
  char* lds_h   = smem + LDS_H_OFF;     // 2 x 4KB ping-pong recurrent h

  const int tid  = threadIdx.x;
  const int w    = tid >> 6;            // wave 0..7, owns units [w*16, w*16+16)
  const int lane = tid & 63;
  const int lrow = lane & 15;           // MFMA row/col lane index
  const int lkg  = lane >> 4;           // MFMA k-group / acc row group
  const int jj   = w * 16 + lrow;       // this lane's unit column

  // ---- weights -> register-resident bf16 B-fragments (one-time) ----
  // B[k][n] = W[gate_row = n][k]; lane: n = lrow, k = kt*32 + lkg*8 + e
  const float* Wih = (KT_IN == 2) ? wih0 : (wihr + (size_t)(layer - 1) * GD * HID);
  const float* Whh = whh + (size_t)layer * GD * HID;

  bf16x8 bfrag[4][KT];
  #pragma unroll
  for (int gt = 0; gt < 4; ++gt) {
    const int gr = gt * 128 + w * 16 + lrow;
    #pragma unroll
    for (int kt = 0; kt < KT; ++kt) {
      short tmp[8];
      #pragma unroll
      for (int eh = 0; eh < 2; ++eh) {
        const int k = kt * 32 + lkg * 8 + eh * 4;
        const float* src = (k < K_IN) ? (Wih + (size_t)gr * K_IN + k)
                                      : (Whh + (size_t)gr * HID + (k - K_IN));
        float4 v = *(const float4*)src;
        tmp[eh*4+0] = f2bf(v.x); tmp[eh*4+1] = f2bf(v.y);
        tmp[eh*4+2] = f2bf(v.z); tmp[eh*4+3] = f2bf(v.w);
      }
      bfrag[gt][kt] = (bf16x8){tmp[0],tmp[1],tmp[2],tmp[3],tmp[4],tmp[5],tmp[6],tmp[7]};
    }
  }

  float bias[4];
  #pragma unroll
  for (int gt = 0; gt < 4; ++gt) {
    const int gr = gt * 128 + w * 16 + lrow;
    bias[gt] = bih[layer * GD + gr] + bhh[layer * GD + gr];
  }

  // ---- init c (f32 regs) and h_{-1} -> lds_h parity 1 ----
  float creg[4], hlast[4];
  {
    #pragma unroll
    for (int r = 0; r < 4; ++r) {
      const int m = lkg * 4 + r;
      const int b = beta * MB + m;
      creg[r]  = c0[((size_t)layer * BATCH + b) * HID + jj];
      float hv = h0[((size_t)layer * BATCH + b) * HID + jj];
      hlast[r] = hv;
      const int byte = (m * 256 + jj * 2) ^ ((m & 7) << 4);
      *(short*)(lds_h + 4096 + byte) = f2bf(hv);
    }
  }

  // ---- flags / rings (interface i = beta*5 + producer_layer) ----
  int*  prog_up = (int*)(ws + PROG_OFF + (size_t)(beta * 5 + layer - 1) * 128);
  int*  prog_dn = (int*)(ws + PROG_OFF + (size_t)(beta * 5 + layer) * 128);
  int*  cons_up = (int*)(ws + CONS_OFF + (size_t)(beta * 5 + layer - 1) * 128);
  int*  cons_dn = (int*)(ws + CONS_OFF + (size_t)(beta * 5 + layer) * 128);
  char* ring_up = ws + RING_OFF + (size_t)(beta * 5 + layer - 1) * IF_BYTES;
  char* ring_dn = ws + RING_OFF + (size_t)(beta * 5 + layer) * IF_BYTES;

  f32x4 accA[4], accB[4];

  for (int q = 0; q < NCHUNKS; ++q) {
    // ================= stage chunk input into lds_in =================
    if (KT_IN == 2) {
      // layer 0: x[b][t][i] f32 -> bf16, swizzled
      const int p = tid >> 1, hh = tid & 1;
      const int s = p >> 4,  m  = p & 15;
      const float* xs = x + ((size_t)(beta * MB + m) * SEQ + (q * CHUNK + s)) * ISZ + hh * 32;
      #pragma unroll
      for (int c4 = 0; c4 < 4; ++c4) {
        float4 a = *(const float4*)(xs + c4 * 8);
        float4 b = *(const float4*)(xs + c4 * 8 + 4);
        bf16x8 pv = {f2bf(a.x), f2bf(a.y), f2bf(a.z), f2bf(a.w),
                     f2bf(b.x), f2bf(b.y), f2bf(b.z), f2bf(b.w)};
        const int byte = s * INB + ((m * RS + hh * 64 + c4 * 16) ^ ((m & 7) << 4));
        *(bf16x8*)(lds_in + byte) = pv;
      }
      __syncthreads();
    } else {
      if (tid == 0) {
        while (__hip_atomic_load(prog_up, __ATOMIC_RELAXED, __HIP_MEMORY_SCOPE_AGENT) < q + 1)
          __builtin_amdgcn_s_sleep(2);
        (void)__hip_atomic_load(prog_up, __ATOMIC_ACQUIRE, __HIP_MEMORY_SCOPE_AGENT);
      }
      __syncthreads();   // acquire (CU L1 inv by tid0's wave, same CU) before loads
      const char* slot = ring_up + (size_t)(q & (NSLOT - 1)) * SLOT_BYTES;
      #pragma unroll
      for (int c = 0; c < 8; ++c) {
        const int L = tid * 128 + c * 16;          // linear ring offset
        int4 v = *(const int4*)(slot + L);
        const int row = (L >> 8) & 15;
        *(int4*)(lds_in + (L ^ ((row & 7) << 4))) = v;  // swizzled LDS
      }
      __syncthreads();
      if (tid == 0)   // ring slot credit back to producer
        __hip_atomic_store(cons_up, q + 1, __ATOMIC_RELEASE, __HIP_MEMORY_SCOPE_AGENT);
    }

    // ================= 16 timesteps (software-pipelined) =================
    INP_PREF(accA, 0);                     // prologue: input half of step 0
    #pragma unroll 1
    for (int s = 0; s < CHUNK; s += 2) {
      DO_STEP(accA, accB, s, 1);
      DO_STEP(accB, accA, s + 1, (s + 1) < (CHUNK - 1));
    }

    // ================= publish chunk to next layer =================
    if (layer < 5) {
      __syncthreads();   // lds_out complete (drains all counters)
      if (tid == 0 && q >= NSLOT) {
        while (__hip_atomic_load(cons_dn, __ATOMIC_RELAXED, __HIP_MEMORY_SCOPE_AGENT) < q + 1 - NSLOT)
          __builtin_amdgcn_s_sleep(2);
        (void)__hip_atomic_load(cons_dn, __ATOMIC_ACQUIRE, __HIP_MEMORY_SCOPE_AGENT);
      }
      __syncthreads();
      char* slot = ring_dn + (size_t)(q & (NSLOT - 1)) * SLOT_BYTES;
      #pragma unroll
      for (int c = 0; c < 8; ++c) {
        const int L = tid * 128 + c * 16;
        const int row = (L >> 8) & 15;
        int4 v = *(const int4*)(lds_out + (L ^ ((row & 7) << 4)));  // unswizzle
        *(int4*)(slot + L) = v;                                     // linear ring
      }
      __syncthreads();   // drains vmcnt: all threads' stores in L2
      if (tid == 0)      // release: wbl2 flush, then flag
        __hip_atomic_store(prog_dn, q + 1, __ATOMIC_RELEASE, __HIP_MEMORY_SCOPE_AGENT);
    }
  }

  // ---- output h_n (f32, from final-step registers) ----
  {
    #pragma unroll
    for (int r = 0; r < 4; ++r) {
      const int m = lkg * 4 + r;
      const int b = beta * MB + m;
      out[((size_t)layer * BATCH + b) * HID + jj] = hlast[r];
    }
  }
}

extern "C" __global__ void __launch_bounds__(512, 2)
lstm_pipe(const float* __restrict__ x,    const float* __restrict__ h0,
          const float* __restrict__ c0,   const float* __restrict__ wih0,
          const float* __restrict__ wihr, const float* __restrict__ whh,
          const float* __restrict__ bih,  const float* __restrict__ bhh,
          float* __restrict__ out, char* __restrict__ ws)
{
  extern __shared__ char smem[];
  const int bid   = blockIdx.x;
  const int beta  = bid & 7;    // chain; bid%8 keeps a chain on one XCD
  const int layer = bid >> 3;
  if (beta >= NCHAIN) return;   // dummy blocks (XCD-alignment padding)
  if (layer == 0)
    lstm_chain<2>(layer, beta, x, h0, c0, wih0, wihr, whh, bih, bhh, out, ws, smem);
  else
    lstm_chain<4>(layer, beta, x, h0, c0, wih0, wihr, whh, bih, bhh, out, ws, smem);
}

extern "C" void kernel_launch(void* const* d_in, const int* in_sizes, int n_in,
                              void* d_out, int out_size, void* d_ws, size_t ws_size,
                              hipStream_t stream)
{
  (void)in_sizes; (void)n_in; (void)out_size; (void)ws_size;
  hipFuncSetAttribute((const void*)lstm_pipe,
                      hipFuncAttributeMaxDynamicSharedMemorySize, LDS_TOTAL);
  // zero progress/consumed flags (d_ws is poisoned 0xAA before every launch)
  hipMemsetAsync(d_ws, 0, RING_OFF, stream);
  lstm_pipe<<<dim3(48), dim3(512), LDS_TOTAL, stream>>>(
      (const float*)d_in[0], (const float*)d_in[1], (const float*)d_in[2],
      (const float*)d_in[3], (const float*)d_in[4], (const float*)d_in[5],
      (const float*)d_in[6], (const float*)d_in[7],
      (float*)d_out, (char*)d_ws);
}

// Round 11
// 2962.867 us; speedup vs baseline: 1.5825x; 1.4961x over previous
//
#include <hip/hip_runtime.h>

// 6-layer LSTM, B=64, S=2048, I=64, H=128, G=512.
// wg = (layer, batch-block of 16). 24 active wgs, layers pipelined via ring
// buffers + agent-scope atomic flags in d_ws (chunked, 16 steps). Weights
// register-resident as bf16 MFMA B-fragments. Recurrent h in LDS (XOR-
// swizzled, ping-pong). R5: SW-pipelined step loop. R6: v_rcp_f32 for all
// divisions (file is not fast-math'd — IEEE div was ~11 VALU ops, 5 per
// unit; R5 counters: VALUBusy 63% active-CU was the bottleneck) + full
// unroll of the 16-step loop (fold s*const into ds offset immediates).

#define NLAYERS 6
#define BATCH   64
#define SEQ     2048
#define ISZ     64
#define HID     128
#define GD      512
#define CHUNK   16
#define NSLOT   2
#define MB      16
#define NCHAIN  4
#define NCHUNKS (SEQ / CHUNK)

#define SLOT_BYTES (CHUNK * MB * HID * 2)   // 65536 B per published chunk
#define IF_BYTES   (NSLOT * SLOT_BYTES)     // 131072 B per interface
#define PROG_OFF   0
#define CONS_OFF   4096
#define RING_OFF   8192
#define LDS_IN_OFF  0
#define LDS_OUT_OFF 65536
#define LDS_H_OFF   131072
#define LDS_TOTAL   139264                  // 136 KiB <= 160 KiB

typedef __attribute__((ext_vector_type(8))) short bf16x8;
typedef __attribute__((ext_vector_type(4))) float f32x4;

__device__ __forceinline__ short f2bf(float f) {
  union { float f; unsigned u; } v; v.f = f;
  unsigned r = v.u + 0x7fffu + ((v.u >> 16) & 1u);   // RNE
  return (short)(r >> 16);
}
__device__ __forceinline__ float frcp(float x)  { return __builtin_amdgcn_rcpf(x); }
// sigm/tanh via v_exp + v_rcp only (no IEEE div sequence)
__device__ __forceinline__ float sigm(float x)  { return frcp(1.0f + __expf(-x)); }
__device__ __forceinline__ float tanh_f(float x){ return 1.0f - 2.0f * frcp(__expf(2.0f * x) + 1.0f); }

// ---- step-loop macros (static acc names; rule #20: no runtime-indexed regs) ----
// Init NXT with bias and accumulate the input-half MFMAs for step SN.
#define INP_PREF(NXT, SN)                                                      \
  do {                                                                         \
    _Pragma("unroll")                                                          \
    for (int gt = 0; gt < 4; ++gt)                                             \
      NXT[gt] = (f32x4){bias[gt], bias[gt], bias[gt], bias[gt]};               \
    _Pragma("unroll")                                                          \
    for (int kt = 0; kt < KT_IN; ++kt) {                                       \
      const int bytei = (SN) * INB + ((lrow * RS + kt * 64 + lkg * 16) ^ ((lrow & 7) << 4)); \
      bf16x8 a = *(const bf16x8*)(lds_in + bytei);                             \
      _Pragma("unroll")                                                        \
      for (int gt = 0; gt < 4; ++gt)                                           \
        NXT[gt] = __builtin_amdgcn_mfma_f32_16x16x32_bf16(a, bfrag[gt][kt], NXT[gt], 0, 0, 0); \
    }                                                                          \
  } while (0)

// One timestep: barrier; recurrent-half MFMA into CUR; (opt) prefetch input
// half of step S+1 into NXT; activations + h/lds_out writes from CUR.
#define DO_STEP(CUR, NXT, S, PREF)                                             \
  do {                                                                         \
    __syncthreads();                                                           \
    {                                                                          \
      char* hsrc = lds_h + ((((S) & 1) ^ 1) << 12);                            \
      _Pragma("unroll")                                                        \
      for (int kt = 0; kt < 4; ++kt) {                                         \
        const int byteh = (lrow * 256 + kt * 64 + lkg * 16) ^ ((lrow & 7) << 4); \
        bf16x8 a = *(const bf16x8*)(hsrc + byteh);                             \
        _Pragma("unroll")                                                      \
        for (int gt = 0; gt < 4; ++gt)                                         \
          CUR[gt] = __builtin_amdgcn_mfma_f32_16x16x32_bf16(a, bfrag[gt][KT_IN + kt], CUR[gt], 0, 0, 0); \
      }                                                                        \
    }                                                                          \
    if (PREF) { INP_PREF(NXT, (S) + 1); }                                      \
    {                                                                          \
      char* hdst = lds_h + (((S) & 1) << 12);                                  \
      _Pragma("unroll")                                                        \
      for (int r = 0; r < 4; ++r) {                                            \
        const float gi = sigm(CUR[0][r]);                                      \
        const float gf = sigm(CUR[1][r]);                                      \
        const float gg = tanh_f(CUR[2][r]);                                    \
        const float go = sigm(CUR[3][r]);                                      \
        const float c  = gf * creg[r] + gi * gg;                               \
        creg[r] = c;                                                           \
        const float h = go * tanh_f(c);                                        \
        hlast[r] = h;                                                          \
        const short hb = f2bf(h);                                              \
        const int m = lkg * 4 + r;                                             \
        const int byteo = (m * 256 + jj * 2) ^ ((m & 7) << 4);                 \
        *(short*)(hdst + byteo) = hb;                                          \
        if (layer < 5) *(short*)(lds_out + (S) * 4096 + byteo) = hb;           \
      }                                                                        \
    }                                                                          \
  } while (0)

template <int KT_IN>
__device__ __forceinline__ void lstm_chain(
    int layer, int beta,
    const float* __restrict__ x,    const float* __restrict__ h0,
    const float* __restrict__ c0,   const float* __restrict__ wih0,
    const float* __restrict__ wihr, const float* __restrict__ whh,
    const float* __restrict__ bih,  const float* __restrict__ bhh,
    float* __restrict__ out, char* __restrict__ ws, char* smem)
{
  constexpr int KT   = KT_IN + 4;       // total K-tiles (32 each)
  constexpr int K_IN = KT_IN * 32;      // 64 (layer 0, from x) or 128
  constexpr int RS   = K_IN * 2;        // lds_in row bytes
  constexpr int INB  = MB * RS;         // lds_in bytes per step-slot

  char* lds_in  = smem + LDS_IN_OFF;    // staged chunk input (16 steps)
  char* lds_out = smem + LDS_OUT_OFF;   // chunk output accumulation
  char* lds_h   = smem + LDS_H_OFF;     // 2 x 4KB ping-pong recurrent h

  const int tid  = threadIdx.x;
  const int w    = tid >> 6;            // wave 0..7, owns units [w*16, w*16+16)
  const int lane = tid & 63;
  const int lrow = lane & 15;           // MFMA row/col lane index
  const int lkg  = lane >> 4;           // MFMA k-group / acc row group
  const int jj   = w * 16 + lrow;       // this lane's unit column

  // ---- weights -> register-resident bf16 B-fragments (one-time) ----
  // B[k][n] = W[gate_row = n][k]; lane: n = lrow, k = kt*32 + lkg*8 + e
  const float* Wih = (KT_IN == 2) ? wih0 : (wihr + (size_t)(layer - 1) * GD * HID);
  const float* Whh = whh + (size_t)layer * GD * HID;

  bf16x8 bfrag[4][KT];
  #pragma unroll
  for (int gt = 0; gt < 4; ++gt) {
    const int gr = gt * 128 + w * 16 + lrow;
    #pragma unroll
    for (int kt = 0; kt < KT; ++kt) {
      short tmp[8];
      #pragma unroll
      for (int eh = 0; eh < 2; ++eh) {
        const int k = kt * 32 + lkg * 8 + eh * 4;
        const float* src = (k < K_IN) ? (Wih + (size_t)gr * K_IN + k)
                                      : (Whh + (size_t)gr * HID + (k - K_IN));
        float4 v = *(const float4*)src;
        tmp[eh*4+0] = f2bf(v.x); tmp[eh*4+1] = f2bf(v.y);
        tmp[eh*4+2] = f2bf(v.z); tmp[eh*4+3] = f2bf(v.w);
      }
      bfrag[gt][kt] = (bf16x8){tmp[0],tmp[1],tmp[2],tmp[3],tmp[4],tmp[5],tmp[6],tmp[7]};
    }
  }

  float bias[4];
  #pragma unroll
  for (int gt = 0; gt < 4; ++gt) {
    const int gr = gt * 128 + w * 16 + lrow;
    bias[gt] = bih[layer * GD + gr] + bhh[layer * GD + gr];
  }

  // ---- init c (f32 regs) and h_{-1} -> lds_h parity 1 ----
  float creg[4], hlast[4];
  {
    #pragma unroll
    for (int r = 0; r < 4; ++r) {
      const int m = lkg * 4 + r;
      const int b = beta * MB + m;
      creg[r]  = c0[((size_t)layer * BATCH + b) * HID + jj];
      float hv = h0[((size_t)layer * BATCH + b) * HID + jj];
      hlast[r] = hv;
      const int byte = (m * 256 + jj * 2) ^ ((m & 7) << 4);
      *(short*)(lds_h + 4096 + byte) = f2bf(hv);
    }
  }

  // ---- flags / rings (interface i = beta*5 + producer_layer) ----
  int*  prog_up = (int*)(ws + PROG_OFF + (size_t)(beta * 5 + layer - 1) * 128);
  int*  prog_dn = (int*)(ws + PROG_OFF + (size_t)(beta * 5 + layer) * 128);
  int*  cons_up = (int*)(ws + CONS_OFF + (size_t)(beta * 5 + layer - 1) * 128);
  int*  cons_dn = (int*)(ws + CONS_OFF + (size_t)(beta * 5 + layer) * 128);
  char* ring_up = ws + RING_OFF + (size_t)(beta * 5 + layer - 1) * IF_BYTES;
  char* ring_dn = ws + RING_OFF + (size_t)(beta * 5 + layer) * IF_BYTES;

  f32x4 accA[4], accB[4];

  for (int q = 0; q < NCHUNKS; ++q) {
    // ================= stage chunk input into lds_in =================
    if (KT_IN == 2) {
      // layer 0: x[b][t][i] f32 -> bf16, swizzled
      const int p = tid >> 1, hh = tid & 1;
      const int s = p >> 4,  m  = p & 15;
      const float* xs = x + ((size_t)(beta * MB + m) * SEQ + (q * CHUNK + s)) * ISZ + hh * 32;
      #pragma unroll
      for (int c4 = 0; c4 < 4; ++c4) {
        float4 a = *(const float4*)(xs + c4 * 8);
        float4 b = *(const float4*)(xs + c4 * 8 + 4);
        bf16x8 pv = {f2bf(a.x), f2bf(a.y), f2bf(a.z), f2bf(a.w),
                     f2bf(b.x), f2bf(b.y), f2bf(b.z), f2bf(b.w)};
        const int byte = s * INB + ((m * RS + hh * 64 + c4 * 16) ^ ((m & 7) << 4));
        *(bf16x8*)(lds_in + byte) = pv;
      }
      __syncthreads();
    } else {
      if (tid == 0) {
        while (__hip_atomic_load(prog_up, __ATOMIC_RELAXED, __HIP_MEMORY_SCOPE_AGENT) < q + 1)
          __builtin_amdgcn_s_sleep(2);
        (void)__hip_atomic_load(prog_up, __ATOMIC_ACQUIRE, __HIP_MEMORY_SCOPE_AGENT);
      }
      __syncthreads();   // acquire ordered before everyone's loads
      const char* slot = ring_up + (size_t)(q & (NSLOT - 1)) * SLOT_BYTES;
      #pragma unroll
      for (int c = 0; c < 8; ++c) {
        const int L = tid * 128 + c * 16;          // linear ring offset
        int4 v = *(const int4*)(slot + L);
        const int row = (L >> 8) & 15;
        *(int4*)(lds_in + (L ^ ((row & 7) << 4))) = v;  // swizzled LDS
      }
      __syncthreads();
      if (tid == 0)   // ring slot credit back to producer
        __hip_atomic_store(cons_up, q + 1, __ATOMIC_RELEASE, __HIP_MEMORY_SCOPE_AGENT);
    }

    // ========== 16 timesteps (SW-pipelined, fully unrolled) ==========
    INP_PREF(accA, 0);                     // prologue: input half of step 0
    #pragma unroll
    for (int s = 0; s < CHUNK; s += 2) {
      DO_STEP(accA, accB, s, 1);
      DO_STEP(accB, accA, s + 1, (s + 1) < (CHUNK - 1));
    }

    // ================= publish chunk to next layer =================
    if (layer < 5) {
      __syncthreads();   // lds_out complete (drains all counters)
      if (tid == 0 && q >= NSLOT) {
        while (__hip_atomic_load(cons_dn, __ATOMIC_RELAXED, __HIP_MEMORY_SCOPE_AGENT) < q + 1 - NSLOT)
          __builtin_amdgcn_s_sleep(2);
        (void)__hip_atomic_load(cons_dn, __ATOMIC_ACQUIRE, __HIP_MEMORY_SCOPE_AGENT);
      }
      __syncthreads();
      char* slot = ring_dn + (size_t)(q & (NSLOT - 1)) * SLOT_BYTES;
      #pragma unroll
      for (int c = 0; c < 8; ++c) {
        const int L = tid * 128 + c * 16;
        const int row = (L >> 8) & 15;
        int4 v = *(const int4*)(lds_out + (L ^ ((row & 7) << 4)));  // unswizzle
        *(int4*)(slot + L) = v;                                     // linear ring
      }
      __syncthreads();   // drains vmcnt: all threads' stores in L2
      if (tid == 0)      // release: wbl2 flush, then flag
        __hip_atomic_store(prog_dn, q + 1, __ATOMIC_RELEASE, __HIP_MEMORY_SCOPE_AGENT);
    }
  }

  // ---- output h_n (f32, from final-step registers) ----
  {
    #pragma unroll
    for (int r = 0; r < 4; ++r) {
      const int m = lkg * 4 + r;
      const int b = beta * MB + m;
      out[((size_t)layer * BATCH + b) * HID + jj] = hlast[r];
    }
  }
}

extern "C" __global__ void __launch_bounds__(512, 2)
lstm_pipe(const float* __restrict__ x,    const float* __restrict__ h0,
          const float* __restrict__ c0,   const float* __restrict__ wih0,
          const float* __restrict__ wihr, const float* __restrict__ whh,
          const float* __restrict__ bih,  const float* __restrict__ bhh,
          float* __restrict__ out, char* __restrict__ ws)
{
  extern __shared__ char smem[];
  const int bid   = blockIdx.x;
  const int beta  = bid & 7;    // chain; bid%8 keeps a chain on one XCD
  const int layer = bid >> 3;
  if (beta >= NCHAIN) return;   // dummy blocks (XCD-alignment padding)
  if (layer == 0)
    lstm_chain<2>(layer, beta, x, h0, c0, wih0, wihr, whh, bih, bhh, out, ws, smem);
  else
    lstm_chain<4>(layer, beta, x, h0, c0, wih0, wihr, whh, bih, bhh, out, ws, smem);
}

extern "C" void kernel_launch(void* const* d_in, const int* in_sizes, int n_in,
                              void* d_out, int out_size, void* d_ws, size_t ws_size,
                              hipStream_t stream)
{
  (void)in_sizes; (void)n_in; (void)out_size; (void)ws_size;
  hipFuncSetAttribute((const void*)lstm_pipe,
                      hipFuncAttributeMaxDynamicSharedMemorySize, LDS_TOTAL);
  // zero progress/consumed flags (d_ws is poisoned 0xAA before every launch)
  hipMemsetAsync(d_ws, 0, RING_OFF, stream);
  lstm_pipe<<<dim3(48), dim3(512), LDS_TOTAL, stream>>>(
      (const float*)d_in[0], (const float*)d_in[1], (const float*)d_in[2],
      (const float*)d_in[3], (const float*)d_in[4], (const float*)d_in[5],
      (const float*)d_in[6], (const float*)d_in[7],
      (float*)d_out, (char*)d_ws);
}